// Round 8
// baseline (9126.151 us; speedup 1.0000x reference)
//
#include <hip/hip_runtime.h>
#include <hip/hip_bf16.h>

#define T_SEQ 512
#define NBATCH 64
#define HID 300
#define G4 1200
#define NTAG 11
#define TAG_START 9
#define TAG_STOP 10
#define NEGV -10000.0f
#define NWGD 38             // lstm WGs per direction, 8 hidden units (= 1 kblock) each
#define NKT 10              // k-tiles of 32 (K padded 300->320)
#define HXE (40*2*64*8)     // u16 per (dir,pp) hx buffer: 40 kblocks x {hi,lo} x 64 b x 8
#define FLGS 16             // u32 stride between flags (64B slots)
#define FLGN 152            // flags per dir = 38 WGs x 4 waves
#define FLGDIR (FLGN*FLGS)
#define SSTEP 16            // pregemm timestep slice

typedef unsigned short u16;
using short8 = __attribute__((ext_vector_type(8))) short;
using f32x4  = __attribute__((ext_vector_type(4))) float;
using f32x16 = __attribute__((ext_vector_type(16))) float;
using i32x4  = __attribute__((ext_vector_type(4))) int;

#define MF(a, b, c)   __builtin_amdgcn_mfma_f32_16x16x32_bf16((a), (b), (c), 0, 0, 0)
#define MF32(a, b, c) __builtin_amdgcn_mfma_f32_32x32x16_bf16((a), (b), (c), 0, 0, 0)

__device__ __forceinline__ float sigf(float x) { return 1.0f / (1.0f + expf(-x)); }

__device__ __forceinline__ u16 f2bf(float x) {
    unsigned u = __float_as_uint(x);
    unsigned r = (u + 0x7FFFu + ((u >> 16) & 1u)) >> 16;   // RNE
    return (u16)r;
}
__device__ __forceinline__ float bf2f(u16 h) {
    return __uint_as_float((unsigned)h << 16);
}

// ---- LLC-coherent (device scope) helpers: sc0 sc1 ----
__device__ __forceinline__ i32x4 ld_cc_x4(const u16* p) {
    i32x4 r;
    asm volatile("global_load_dwordx4 %0, %1, off sc0 sc1" : "=v"(r) : "v"(p) : "memory");
    return r;
}
__device__ __forceinline__ unsigned ld_cc_b32(const unsigned* p) {
    unsigned r;
    asm volatile("global_load_dword %0, %1, off sc0 sc1\n\t"
                 "s_waitcnt vmcnt(0)" : "=v"(r) : "v"(p) : "memory");
    return r;
}
__device__ __forceinline__ void st_cc_x4(u16* p, i32x4 v) {
    asm volatile("global_store_dwordx4 %0, %1, off sc0 sc1" :: "v"(p), "v"(v) : "memory");
}
__device__ __forceinline__ void st_cc_b32(unsigned* p, unsigned v) {
    asm volatile("global_store_dword %0, %1, off sc0 sc1" :: "v"(p), "v"(v) : "memory");
}
__device__ __forceinline__ void wait_vm0() {
    asm volatile("s_waitcnt vmcnt(0)" ::: "memory");
}

// ---------- embedding gather -> block layout xs0[t][40][64][2][8] (hi8|lo8 u16) ----------
__global__ __launch_bounds__(256) void k_gather(const int* __restrict__ x,
                                                const float* __restrict__ emb,
                                                u16* __restrict__ xs0)
{
    int t = blockIdx.x;
    __shared__ int rid[NBATCH];
    if (threadIdx.x < NBATCH) rid[threadIdx.x] = x[threadIdx.x * T_SEQ + t];
    __syncthreads();
    for (int o = threadIdx.x; o < 64 * 40; o += 256) {
        int b = o / 40, m8 = o - b * 40;
        unsigned hw[4], lw[4];
#pragma unroll
        for (int p = 0; p < 4; ++p) {
            int k0 = m8 * 8 + p * 2;
            float v0 = (k0 < 300)     ? emb[(size_t)rid[b] * 300 + k0]     : 0.0f;
            float v1 = (k0 + 1 < 300) ? emb[(size_t)rid[b] * 300 + k0 + 1] : 0.0f;
            u16 h0 = f2bf(v0), h1 = f2bf(v1);
            u16 l0 = f2bf(v0 - bf2f(h0)), l1 = f2bf(v1 - bf2f(h1));
            hw[p] = (unsigned)h0 | ((unsigned)h1 << 16);
            lw[p] = (unsigned)l0 | ((unsigned)l1 << 16);
        }
        u16* dst = xs0 + (((size_t)t * 40 + m8) * 64 + b) * 16;
        *(i32x4*)dst       = i32x4{(int)hw[0], (int)hw[1], (int)hw[2], (int)hw[3]};
        *(i32x4*)(dst + 8) = i32x4{(int)lw[0], (int)lw[1], (int)lw[2], (int)lw[3]};
    }
}

// ---------- zero xs1 pad blocks 76..79 ----------
__global__ __launch_bounds__(256) void k_zpad(u16* __restrict__ xs1)
{
    int t = blockIdx.x;
    i32x4* base = (i32x4*)(xs1 + (((size_t)t * 80 + 76) * 64) * 16);
    i32x4 z = {0, 0, 0, 0};
    for (int o = threadIdx.x; o < 4 * 64 * 2; o += 256) base[o] = z;
}

// ---------- pregemm v2: 32x32x16 MFMA, 19 WGs/dir/segment ----------
// X-traffic per WG-step = 160KB covering 64 j-gate rows (vs 80KB/16 rows in
// v1): ~3.9x less LLC read volume. Wave wv: jblk = jpair*2 + (wv>>1) (8 j
// units x 4 gates = 32 M-rows), bhalf = wv&1 (32 batch cols).
// Fragment maps: A: lane l -> row l&31, k = ks*16 + (l>>5)*8 + e  [mirrors
// proven 16x16x32 mapping]. B: col l&31, same k (xs block = B0+2ks+(l>>5),
// elem e, batch = bhalf*32+(l&31)). C/D (HW-measured m74/m101): col=lane&31,
// row=(reg&3)+8*(reg>>2)+4*(lane>>5).
// Segments: layer0 = 1 seg (blocks 0..39, Wi cols 0..299); layer1 = 2 segs:
// seg0 blocks 0..37 (fwd h, cols 0..299), seg1 blocks 38..75 (bwd h, cols
// 300..599); pads are zero; weights zeroed for u>=300 per segment. Bias
// added in seg0 only. Outputs to per-seg pre buffers; lstm sums for layer1.
__global__ __launch_bounds__(256) void k_pregemm2(
    const u16* __restrict__ xs, int TNB, int NSEG,
    const float* __restrict__ WiF, const float* __restrict__ WiB, int KMAXW,
    const float* __restrict__ biF, const float* __restrict__ bhF,
    const float* __restrict__ biB, const float* __restrict__ bhB,
    float* __restrict__ p0F, float* __restrict__ p0B,
    float* __restrict__ p1F, float* __restrict__ p1B,
    int t0f, int t0b, int NSL, int C)
{
    int bx = blockIdx.x;
    int unit = bx / (2 * NSL);
    int rem = bx - unit * 2 * NSL;
    int seg = unit / 19;
    int jpair = unit - seg * 19;
    int sl = rem >> 1, dir = rem & 1;
    int s0 = sl * SSTEP, s1 = min(s0 + SSTEP, C);
    (void)NSEG;

    int B0 = seg * 38;
    int KOFF = seg * 300;
    int addb = (seg == 0);
    const float* Wi = dir ? WiB : WiF;
    const float* bi = dir ? biB : biF;
    const float* bh = dir ? bhB : bhF;
    float* pre = seg ? (dir ? p1B : p1F) : (dir ? p0B : p0F);

    int tid = threadIdx.x;
    int wv = tid >> 6, l = tid & 63;
    int jb = jpair * 2 + (wv >> 1);      // jblk 0..37 (8 units each)
    int bhalf = wv & 1;
    int lo5 = l & 31, hi5 = l >> 5;
    int bcol = bhalf * 32 + lo5;

    // A fragments (hi/lo planes), resident
    short8 aH2[20], aL2[20];
    {
        int g = lo5 & 3, uo = lo5 >> 2;
        int jrow = jb * 8 + uo;
        bool jok = jrow < 300;
        const float* wr = Wi + ((size_t)g * 300 + (jok ? jrow : 0)) * KMAXW + KOFF;
#pragma unroll
        for (int ks = 0; ks < 20; ++ks) {
            short8 vh, vl;
#pragma unroll
            for (int e = 0; e < 8; ++e) {
                int u = ks * 16 + hi5 * 8 + e;
                float w = (jok && u < 300) ? wr[u] : 0.0f;
                u16 hb = f2bf(w);
                vh[e] = (short)hb;
                vl[e] = (short)f2bf(w - bf2f(hb));
            }
            aH2[ks] = vh; aL2[ks] = vl;
        }
    }
    // per-acc-reg output offsets + bias (constant across steps)
    int oaddr[16]; float brg[16]; bool ovld[16];
#pragma unroll
    for (int r = 0; r < 16; ++r) {
        int m = (r & 3) + 8 * (r >> 2) + 4 * hi5;
        int gg = m & 3, u2 = m >> 2;
        int jr = jb * 8 + u2;
        ovld[r] = jr < 300;
        int jc = ovld[r] ? jr : 0;
        oaddr[r] = (gg * 300 + jc) * 64 + bcol;
        brg[r] = addb ? (bi[gg * 300 + jc] + bh[gg * 300 + jc]) : 0.0f;
    }

    for (int s = s0; s < s1; ++s) {
        int t = dir ? (t0b - s) : (t0f + s);
        const u16* bt = xs + (((size_t)t * TNB + B0) * 64) * 16;
        short8 bhv[20], blv[20];
#pragma unroll
        for (int ks = 0; ks < 20; ++ks) {
            const u16* gp = bt + ((size_t)(2 * ks + hi5) * 64 + bcol) * 16;
            bhv[ks] = *(const short8*)gp;
            blv[ks] = *(const short8*)(gp + 8);
        }
        f32x16 aA = {0.f,0.f,0.f,0.f,0.f,0.f,0.f,0.f,0.f,0.f,0.f,0.f,0.f,0.f,0.f,0.f};
        f32x16 aB = {0.f,0.f,0.f,0.f,0.f,0.f,0.f,0.f,0.f,0.f,0.f,0.f,0.f,0.f,0.f,0.f};
        f32x16 aC = {0.f,0.f,0.f,0.f,0.f,0.f,0.f,0.f,0.f,0.f,0.f,0.f,0.f,0.f,0.f,0.f};
#pragma unroll
        for (int ks = 0; ks < 20; ++ks) {
            aA = MF32(aH2[ks], bhv[ks], aA);
            aB = MF32(aL2[ks], bhv[ks], aB);
        }
#pragma unroll
        for (int ks = 0; ks < 20; ++ks)
            aC = MF32(aH2[ks], blv[ks], aC);
        float* po = pre + (size_t)s * (G4 * 64);
#pragma unroll
        for (int r = 0; r < 16; ++r)
            if (ovld[r]) po[oaddr[r]] = aA[r] + aB[r] + aC[r] + brg[r];
    }
}

// ---------- lstm role: r3-proven (sharded poll + LDS combine) ----------
// MODE==0 (layer1): pre = seg0 + seg1 partial sums.
template<int MODE>
__device__ __forceinline__ void lstm_role(
    const float* __restrict__ preF, const float* __restrict__ preB,
    const float* __restrict__ pre2F, const float* __restrict__ pre2B,
    const float* __restrict__ WhF, const float* __restrict__ WhB,
    u16* __restrict__ hx, float* __restrict__ cbuf,
    float* __restrict__ xs2, u16* __restrict__ xs1,
    int t0f, int t0b, int C, int first,
    unsigned* __restrict__ flags,
    volatile unsigned* wgprog,
    int bid, int tid)
{
    __builtin_amdgcn_s_setprio(1);
    int dir = bid & 1, idx = bid >> 1;   // idx 0..37
    const float* pre  = dir ? preB  : preF;
    const float* pre2 = dir ? pre2B : pre2F;
    const float* Wh  = dir ? WhB : WhF;
    u16* hxd = hx + (size_t)dir * 2 * HXE;
    float* cb = cbuf + (size_t)dir * 300 * 64;
    unsigned* flg = flags + (size_t)dir * FLGDIR;
    int w = tid >> 6, l = tid & 63;
    int hh = l >> 4, kbx = l >> 4;
    int bcol = w * 16 + (l & 15);
    int j0 = idx * 8;
    int ju0 = j0 + hh, ju1 = j0 + 4 + hh;
    int jc0 = min(ju0, 299), jc1 = min(ju1, 299);
    bool jv0 = ju0 < 300, jv1 = ju1 < 300;

    unsigned* myflag = flg + (size_t)(idx * 4 + w) * FLGS;
    const unsigned* shardp = flg + (size_t)(w * 38 + min(l, 37)) * FLGS;
    bool shact = l < 38;

    if (l == 0) wgprog[w] = 0;
    __syncthreads();

    // A fragments (2 stripes x hi/lo), preloaded once
    short8 aH[2][NKT], aL[2][NKT];
    {
        int r = l & 15;
        int g = r & 3, uo = r >> 2;
#pragma unroll
        for (int q = 0; q < 2; ++q) {
            int jr = j0 + q * 4 + uo;
            const float* wr = Wh + ((size_t)g * 300 + min(jr, 299)) * 300;
            bool jvr = jr < 300;
#pragma unroll
            for (int kt = 0; kt < NKT; ++kt) {
                short8 vh, vl;
#pragma unroll
                for (int e = 0; e < 8; ++e) {
                    int k = kt * 32 + kbx * 8 + e;
                    float wv = (jvr && k < 300) ? wr[k] : 0.0f;
                    u16 hb = f2bf(wv);
                    vh[e] = (short)hb;
                    vl[e] = (short)f2bf(wv - bf2f(hb));
                }
                aH[q][kt] = vh; aL[q][kt] = vl;
            }
        }
    }
    float c0 = first ? 0.0f : cb[(size_t)jc0 * 64 + bcol];
    float c1 = first ? 0.0f : cb[(size_t)jc1 * 64 + bcol];

    float p0[4], p1[4];
#pragma unroll
    for (int g = 0; g < 4; ++g) {
        size_t o0 = ((size_t)g * 300 + jc0) * 64 + bcol;
        size_t o1 = ((size_t)g * 300 + jc1) * 64 + bcol;
        p0[g] = pre[o0]; p1[g] = pre[o1];
        if (MODE == 0) { p0[g] += pre2[o0]; p1[g] += pre2[o1]; }
    }

    int pp = 0;
    for (int s = 0; s < C; ++s) {
        f32x4 aA0 = {0.f,0.f,0.f,0.f}, aB0 = {0.f,0.f,0.f,0.f}, aC0 = {0.f,0.f,0.f,0.f};
        f32x4 aA1 = {0.f,0.f,0.f,0.f}, aB1 = {0.f,0.f,0.f,0.f}, aC1 = {0.f,0.f,0.f,0.f};
        if (!(first && s == 0)) {
            const u16* hxr = hxd + (size_t)pp * HXE;
            i32x4 bh[NKT], bl[NKT];
#pragma unroll
            for (int kt = 0; kt < NKT; ++kt) {
                const u16* gp = hxr + (size_t)(4 * kt + kbx) * 1024 + (size_t)bcol * 8;
                bh[kt] = ld_cc_x4(gp);
            }
#pragma unroll
            for (int kt = 0; kt < NKT; ++kt) {
                const u16* gp = hxr + (size_t)(4 * kt + kbx) * 1024 + (size_t)bcol * 8;
                bl[kt] = ld_cc_x4(gp + 512);
            }
            asm volatile("s_waitcnt vmcnt(10)" ::: "memory");
            __builtin_amdgcn_sched_barrier(0);
#pragma unroll
            for (int kt = 0; kt < NKT; ++kt) {
                short8 bhv = __builtin_bit_cast(short8, bh[kt]);
                aA0 = MF(aH[0][kt], bhv, aA0);
                aB0 = MF(aL[0][kt], bhv, aB0);
                aA1 = MF(aH[1][kt], bhv, aA1);
                aB1 = MF(aL[1][kt], bhv, aB1);
            }
            wait_vm0();
            __builtin_amdgcn_sched_barrier(0);
#pragma unroll
            for (int kt = 0; kt < NKT; ++kt) {
                short8 blv = __builtin_bit_cast(short8, bl[kt]);
                aC0 = MF(aH[0][kt], blv, aC0);
                aC1 = MF(aH[1][kt], blv, aC1);
            }
        }
        float hv0, hv1;
        {
            float gi = sigf(aA0[0] + aB0[0] + aC0[0] + p0[0]);
            float gf = sigf(aA0[1] + aB0[1] + aC0[1] + p0[1]);
            float gg = tanhf(aA0[2] + aB0[2] + aC0[2] + p0[2]);
            float go = sigf(aA0[3] + aB0[3] + aC0[3] + p0[3]);
            c0 = gf * c0 + gi * gg;
            hv0 = go * tanhf(c0);
            if (!jv0) hv0 = 0.0f;
        }
        {
            float gi = sigf(aA1[0] + aB1[0] + aC1[0] + p1[0]);
            float gf = sigf(aA1[1] + aB1[1] + aC1[1] + p1[1]);
            float gg = tanhf(aA1[2] + aB1[2] + aC1[2] + p1[2]);
            float go = sigf(aA1[3] + aB1[3] + aC1[3] + p1[3]);
            c1 = gf * c1 + gi * gg;
            hv1 = go * tanhf(c1);
            if (!jv1) hv1 = 0.0f;
        }
        u16 hb0 = f2bf(hv0);
        unsigned pk0 = (unsigned)hb0 | ((unsigned)f2bf(hv0 - bf2f(hb0)) << 16);
        u16 hb1 = f2bf(hv1);
        unsigned pk1 = (unsigned)hb1 | ((unsigned)f2bf(hv1 - bf2f(hb1)) << 16);
        int ls = l & 15;
        unsigned a0 = __shfl(pk0, ls), a1 = __shfl(pk0, ls + 16), a2 = __shfl(pk0, ls + 32), a3 = __shfl(pk0, ls + 48);
        unsigned b0 = __shfl(pk1, ls), b1 = __shfl(pk1, ls + 16), b2 = __shfl(pk1, ls + 32), b3 = __shfl(pk1, ls + 48);
        i32x4 hi4 = {(int)((a0 & 0xffffu) | (a1 << 16)), (int)((a2 & 0xffffu) | (a3 << 16)),
                     (int)((b0 & 0xffffu) | (b1 << 16)), (int)((b2 & 0xffffu) | (b3 << 16))};
        i32x4 lo4 = {(int)((a0 >> 16) | (a1 & 0xffff0000u)), (int)((a2 >> 16) | (a3 & 0xffff0000u)),
                     (int)((b0 >> 16) | (b1 & 0xffff0000u)), (int)((b2 >> 16) | (b3 & 0xffff0000u))};
        int t = dir ? (t0b - s) : (t0f + s);
        if (l < 16) {
            int b = w * 16 + l;
            u16* hxw = hxd + (size_t)(pp ^ 1) * HXE + (size_t)idx * 1024 + (size_t)b * 8;
            st_cc_x4(hxw, hi4);
            st_cc_x4(hxw + 512, lo4);
        }
        wait_vm0();
        if (l == 0) st_cc_b32(myflag, (unsigned)(s + 1));
        if (MODE == 0) {
            if (jv0) xs2[((size_t)t * 600 + dir * 300 + ju0) * 64 + bcol] = hv0;
            if (jv1) xs2[((size_t)t * 600 + dir * 300 + ju1) * 64 + bcol] = hv1;
        } else if (l < 16) {
            int b = w * 16 + l;
            u16* xd = xs1 + (((size_t)t * 80 + dir * 38 + idx) * 64 + b) * 16;
            *(i32x4*)xd       = hi4;
            *(i32x4*)(xd + 8) = lo4;
        }
        if (s + 1 < C) {
#pragma unroll
            for (int g = 0; g < 4; ++g) {
                size_t o0 = ((size_t)(s + 1) * G4 + (size_t)g * 300 + jc0) * 64 + bcol;
                size_t o1 = ((size_t)(s + 1) * G4 + (size_t)g * 300 + jc1) * 64 + bcol;
                p0[g] = pre[o0]; p1[g] = pre[o1];
                if (MODE == 0) { p0[g] += pre2[o0]; p1[g] += pre2[o1]; }
            }
            unsigned tgt = (unsigned)(s + 1);
            unsigned ok;
            do {
                unsigned v = tgt;
                if (shact) v = ld_cc_b32(shardp);
                ok = (v >= tgt) ? 1u : 0u;
            } while (!__all(ok));
            if (l == 0) wgprog[w] = tgt;
            while (!(wgprog[0] >= tgt && wgprog[1] >= tgt &&
                     wgprog[2] >= tgt && wgprog[3] >= tgt)) {
                __builtin_amdgcn_s_sleep(1);
            }
        }
        pp ^= 1;
    }
    if (jv0) cb[(size_t)jc0 * 64 + bcol] = c0;
    if (jv1) cb[(size_t)jc1 * 64 + bcol] = c1;
}

// ---------- chunk kernel: 76 lstm WGs only ----------
template<int MODE>
__global__ __launch_bounds__(256, 1) void k_chunk(
    const float* __restrict__ preF, const float* __restrict__ preB,
    const float* __restrict__ pre2F, const float* __restrict__ pre2B,
    const float* __restrict__ WhF, const float* __restrict__ WhB,
    u16* __restrict__ hx, float* __restrict__ cbuf,
    float* __restrict__ xs2, u16* __restrict__ xs1,
    int t0f, int t0b, int C, int first,
    unsigned* __restrict__ flags)
{
    __shared__ unsigned wgprog[4];
    lstm_role<MODE>(preF, preB, pre2F, pre2B, WhF, WhB, hx, cbuf, xs2, xs1,
                    t0f, t0b, C, first, flags, wgprog, blockIdx.x, threadIdx.x);
}

// ---------- output projection: feats[t][g][b] ----------
__global__ __launch_bounds__(256) void k_feats(
    const float* __restrict__ xs2, const float* __restrict__ Wout,
    const float* __restrict__ bout, float* __restrict__ feats)
{
    int t = blockIdx.x;
    int tid = threadIdx.x;
    int b = tid & 63, g0 = tid >> 6;
    const float* xa = xs2 + (size_t)t * 600 * 64 + b;
    for (int g = g0; g < NTAG; g += 4) {
        float acc = bout[g];
        const float* wr = Wout + (size_t)g * 600;
#pragma unroll 4
        for (int k = 0; k < 600; ++k) acc += wr[k] * xa[(size_t)k * 64];
        feats[((size_t)t * NTAG + g) * 64 + b] = acc;
    }
}

// ---------- Viterbi ----------
__global__ __launch_bounds__(256) void k_viterbi(
    const float* __restrict__ feats, const float* __restrict__ trans,
    float* __restrict__ out)
{
    __shared__ unsigned char bp[4][T_SEQ * NTAG];
    int tid = threadIdx.x;
    int wv = tid >> 6, lane = tid & 63;
    int b = blockIdx.x * 4 + wv;
    int i = (lane < NTAG) ? lane : 0;
    bool act = lane < NTAG;
    float trow[NTAG];
#pragma unroll
    for (int j = 0; j < NTAG; ++j) trow[j] = trans[i * NTAG + j];
    float fv = (lane == TAG_START) ? 0.0f : NEGV;
    for (int t = 0; t < T_SEQ; ++t) {
        float m = -3.0e38f; int arg = 0;
#pragma unroll
        for (int j = 0; j < NTAG; ++j) {
            float fvj = __shfl(fv, j, 64);
            float sc = fvj + trow[j];
            if (sc > m) { m = sc; arg = j; }
        }
        float ft = feats[((size_t)t * NTAG + i) * 64 + b];
        fv = m + ft;
        if (act) bp[wv][t * NTAG + lane] = (unsigned char)arg;
    }
    float term = act ? (fv + trans[TAG_STOP * NTAG + i]) : -3.0e38f;
    int bi_ = lane;
#pragma unroll
    for (int off = 32; off >= 1; off >>= 1) {
        float ov = __shfl_xor(term, off, 64);
        int oi = __shfl_xor(bi_, off, 64);
        if (ov > term || (ov == term && oi < bi_)) { term = ov; bi_ = oi; }
    }
    if (lane == 0) {
        out[b] = term;
        int tag = bi_;
        float* po = out + 64 + (size_t)b * T_SEQ;
        for (int t = T_SEQ - 1; t >= 0; --t) {
            po[t] = (float)tag;
            tag = bp[wv][t * NTAG + tag];
        }
    }
}

extern "C" void kernel_launch(void* const* d_in, const int* in_sizes, int n_in,
                              void* d_out, int out_size, void* d_ws, size_t ws_size,
                              hipStream_t stream)
{
    (void)in_sizes; (void)n_in; (void)out_size;
    const int*   x     = (const int*)d_in[0];
    const float* emb   = (const float*)d_in[1];
    const float* Wout  = (const float*)d_in[2];
    const float* bout  = (const float*)d_in[3];
    const float* trans = (const float*)d_in[4];

    float* ws = (float*)d_ws;
    const size_t XS2F = (size_t)T_SEQ * 600 * NBATCH;          // f32
    const size_t XS1U = (size_t)T_SEQ * 80 * 64 * 16;          // u16
    const size_t FEA  = (size_t)T_SEQ * NTAG * NBATCH;

    float* xs2 = ws;                          // layer-1 f32 output (aliases xs0 blocks)
    u16* xs0 = (u16*)ws;                      // [T][40][64][2][8]
    u16* xs1 = (u16*)(ws + XS2F);             // [T][80][64][2][8]
    float* featB = (float*)(xs1 + XS1U);
    float* cB = featB + FEA;                  // 2*300*64
    u16* hxB = (u16*)(cB + 2 * 300 * 64);     // 4*HXE
    unsigned* flagsB = (unsigned*)(hxB + 4 * HXE);   // 64 slots * 2 dirs * FLGDIR
    unsigned* padB = flagsB + 64ULL * 2 * FLGDIR;    // layout hole kept (16 u32)
    float* preBase = (float*)(padB + 16);
    size_t fixedBytes = (size_t)((char*)preBase - (char*)ws);

    // two ping-pong pre slots; each slot = 2 segs x 2 dirs x Cmax*G4*64 floats
    int Cmax = 512;
    while (Cmax > 16 && fixedBytes + 32ULL * Cmax * G4 * NBATCH > ws_size) Cmax >>= 1;
    size_t Q = (size_t)Cmax * G4 * NBATCH;    // floats per (seg,dir) buf
    size_t slotF = 4 * Q;
    float* preS[2] = { preBase, preBase + slotF };

    // chunk schedule: small first chunk shrinks the first exposed pregemm
    int sizes[40], off[41], nch = 0;
    {
        int rem = T_SEQ;
        int f = (Cmax >= 64) ? 32 : Cmax;
        sizes[nch++] = f; rem -= f;
        while (rem > 0) { int s = rem < Cmax ? rem : Cmax; sizes[nch++] = s; rem -= s; }
        off[0] = 0;
        for (int i = 0; i < nch; ++i) off[i + 1] = off[i] + sizes[i];
    }

    (void)hipMemsetAsync(hxB, 0,
        4 * HXE * sizeof(u16) + (64ULL * 2 * FLGDIR) * sizeof(unsigned), stream);
    k_gather<<<T_SEQ, 256, 0, stream>>>(x, emb, xs0);
    k_zpad<<<T_SEQ, 256, 0, stream>>>(xs1);

    for (int layer = 0; layer < 2; ++layer) {
        int base = 5 + layer * 8;
        const float* WiF = (const float*)d_in[base + 0];
        const float* WhF = (const float*)d_in[base + 1];
        const float* biF = (const float*)d_in[base + 2];
        const float* bhF = (const float*)d_in[base + 3];
        const float* WiB = (const float*)d_in[base + 4];
        const float* WhB = (const float*)d_in[base + 5];
        const float* biB = (const float*)d_in[base + 6];
        const float* bhB = (const float*)d_in[base + 7];
        const u16* xsL = (layer == 0) ? xs0 : xs1;
        int TNB = (layer == 0) ? 40 : 80;
        int NSEG = (layer == 0) ? 1 : 2;
        int KMW = (layer == 0) ? 300 : 600;

        // chunk-0 pregemm (slot 0)
        {
            int NSL0 = (sizes[0] + SSTEP - 1) / SSTEP;
            float* p = preS[0];
            k_pregemm2<<<19 * NSEG * 2 * NSL0, 256, 0, stream>>>(
                xsL, TNB, NSEG, WiF, WiB, KMW, biF, bhF, biB, bhB,
                p, p + Q, p + 2 * Q, p + 3 * Q,
                0, T_SEQ - 1, NSL0, sizes[0]);
        }

        for (int ci = 0; ci < nch; ++ci) {
            int cur = ci & 1, nxt = cur ^ 1;
            int t0f = off[ci], t0b = (T_SEQ - 1) - off[ci];
            int slot = layer * 32 + ci;
            unsigned* flags = flagsB + (size_t)slot * 2 * FLGDIR;
            float* pc = preS[cur];
            if (layer == 0)
                k_chunk<1><<<2 * NWGD, 256, 0, stream>>>(
                    pc, pc + Q, pc + 2 * Q, pc + 3 * Q, WhF, WhB, hxB, cB,
                    xs2, xs1, t0f, t0b, sizes[ci], (ci == 0) ? 1 : 0, flags);
            else
                k_chunk<0><<<2 * NWGD, 256, 0, stream>>>(
                    pc, pc + Q, pc + 2 * Q, pc + 3 * Q, WhF, WhB, hxB, cB,
                    xs2, xs1, t0f, t0b, sizes[ci], (ci == 0) ? 1 : 0, flags);

            // serial pregemm for chunk ci+1
            if (ci + 1 < nch) {
                int CN = sizes[ci + 1];
                int NSLn = (CN + SSTEP - 1) / SSTEP;
                int t0fN = off[ci + 1], t0bN = (T_SEQ - 1) - off[ci + 1];
                float* pn = preS[nxt];
                k_pregemm2<<<19 * NSEG * 2 * NSLn, 256, 0, stream>>>(
                    xsL, TNB, NSEG, WiF, WiB, KMW, biF, bhF, biB, bhB,
                    pn, pn + Q, pn + 2 * Q, pn + 3 * Q,
                    t0fN, t0bN, NSLn, CN);
            }
        }
    }
    k_feats<<<T_SEQ, 256, 0, stream>>>(xs2, Wout, bout, featB);
    k_viterbi<<<16, 256, 0, stream>>>(featB, trans, (float*)d_out);
}

// Round 9
// 7062.566 us; speedup vs baseline: 1.2922x; 1.2922x over previous
//
#include <hip/hip_runtime.h>
#include <hip/hip_bf16.h>

#define T_SEQ 512
#define NBATCH 64
#define HID 300
#define G4 1200
#define NTAG 11
#define TAG_START 9
#define TAG_STOP 10
#define NEGV -10000.0f
#define NWGD 38             // lstm WGs per direction, 8 hidden units (= 1 kblock) each
#define NKT 10              // k-tiles of 32 (K padded 300->320)
#define HXE (40*2*64*8)     // u16 per (dir,pp) hx buffer: 40 kblocks x {hi,lo} x 64 b x 8
#define FLGS 16             // u32 stride between flags (64B slots)
#define FLGN 152            // flags per dir = 38 WGs x 4 waves
#define FLGDIR (FLGN*FLGS)
#define SSTEP 16            // pregemm timestep slice
#define NCOMP 80            // companion WGs in fused kernel (max 20 units x 4 slices)

typedef unsigned short u16;
using short8 = __attribute__((ext_vector_type(8))) short;
using f32x4  = __attribute__((ext_vector_type(4))) float;
using f32x16 = __attribute__((ext_vector_type(16))) float;
using i32x4  = __attribute__((ext_vector_type(4))) int;

#define MF(a, b, c)   __builtin_amdgcn_mfma_f32_16x16x32_bf16((a), (b), (c), 0, 0, 0)
#define MF32(a, b, c) __builtin_amdgcn_mfma_f32_32x32x16_bf16((a), (b), (c), 0, 0, 0)

__device__ __forceinline__ float sigf(float x) { return 1.0f / (1.0f + expf(-x)); }

__device__ __forceinline__ u16 f2bf(float x) {
    unsigned u = __float_as_uint(x);
    unsigned r = (u + 0x7FFFu + ((u >> 16) & 1u)) >> 16;   // RNE
    return (u16)r;
}
__device__ __forceinline__ float bf2f(u16 h) {
    return __uint_as_float((unsigned)h << 16);
}
__device__ __forceinline__ f32x16 zero16() {
    f32x16 z = {0.f,0.f,0.f,0.f,0.f,0.f,0.f,0.f,0.f,0.f,0.f,0.f,0.f,0.f,0.f,0.f};
    return z;
}

// ---- LLC-coherent (device scope) helpers: sc0 sc1 ----
__device__ __forceinline__ i32x4 ld_cc_x4(const u16* p) {
    i32x4 r;
    asm volatile("global_load_dwordx4 %0, %1, off sc0 sc1" : "=v"(r) : "v"(p) : "memory");
    return r;
}
__device__ __forceinline__ unsigned ld_cc_b32(const unsigned* p) {
    unsigned r;
    asm volatile("global_load_dword %0, %1, off sc0 sc1\n\t"
                 "s_waitcnt vmcnt(0)" : "=v"(r) : "v"(p) : "memory");
    return r;
}
__device__ __forceinline__ void st_cc_x4(u16* p, i32x4 v) {
    asm volatile("global_store_dwordx4 %0, %1, off sc0 sc1" :: "v"(p), "v"(v) : "memory");
}
__device__ __forceinline__ void st_cc_b32(unsigned* p, unsigned v) {
    asm volatile("global_store_dword %0, %1, off sc0 sc1" :: "v"(p), "v"(v) : "memory");
}
__device__ __forceinline__ void wait_vm0() {
    asm volatile("s_waitcnt vmcnt(0)" ::: "memory");
}

// ---------- embedding gather -> block layout xs0[t][40][64][2][8] (hi8|lo8 u16) ----------
__global__ __launch_bounds__(256) void k_gather(const int* __restrict__ x,
                                                const float* __restrict__ emb,
                                                u16* __restrict__ xs0)
{
    int t = blockIdx.x;
    __shared__ int rid[NBATCH];
    if (threadIdx.x < NBATCH) rid[threadIdx.x] = x[threadIdx.x * T_SEQ + t];
    __syncthreads();
    for (int o = threadIdx.x; o < 64 * 40; o += 256) {
        int b = o / 40, m8 = o - b * 40;
        unsigned hw[4], lw[4];
#pragma unroll
        for (int p = 0; p < 4; ++p) {
            int k0 = m8 * 8 + p * 2;
            float v0 = (k0 < 300)     ? emb[(size_t)rid[b] * 300 + k0]     : 0.0f;
            float v1 = (k0 + 1 < 300) ? emb[(size_t)rid[b] * 300 + k0 + 1] : 0.0f;
            u16 h0 = f2bf(v0), h1 = f2bf(v1);
            u16 l0 = f2bf(v0 - bf2f(h0)), l1 = f2bf(v1 - bf2f(h1));
            hw[p] = (unsigned)h0 | ((unsigned)h1 << 16);
            lw[p] = (unsigned)l0 | ((unsigned)l1 << 16);
        }
        u16* dst = xs0 + (((size_t)t * 40 + m8) * 64 + b) * 16;
        *(i32x4*)dst       = i32x4{(int)hw[0], (int)hw[1], (int)hw[2], (int)hw[3]};
        *(i32x4*)(dst + 8) = i32x4{(int)lw[0], (int)lw[1], (int)lw[2], (int)lw[3]};
    }
}

// ---------- zero xs1 pad blocks 76..79 ----------
__global__ __launch_bounds__(256) void k_zpad(u16* __restrict__ xs1)
{
    int t = blockIdx.x;
    i32x4* base = (i32x4*)(xs1 + (((size_t)t * 80 + 76) * 64) * 16);
    i32x4 z = {0, 0, 0, 0};
    for (int o = threadIdx.x; o < 4 * 64 * 2; o += 256) base[o] = z;
}

// ---------- pregemm v3: 32x32x16 MFMA, 128 rows/WG (4 jblk waves x 2 bhalf passes) ----------
// Unit = (jquad, dir); jb = jquad*4 + wave. All 4 waves stream the SAME B slab
// (L1/L2 dedup) -> LLC traffic = slab x 10 units/dir/step (7.5x below v1).
// Unified K for layer1 (NKS=40) using v1's proven concat-k column map:
// valid=(u<300)||(304<=u<604), cc = u<300 ? u : u-4. NO bias here (lstm adds).
// Fragment maps verbatim from r7 (refcheck-proven): A row=l&31, k=(l>>5)*8+e;
// B col=l&31 (+bhalf*32), same k; C/D col=l&31, row=(r&3)+8*(r>>2)+4*(l>>5).
template<int NKS, int KMAXW>
__device__ __forceinline__ void pregemm3_role(
    const u16* __restrict__ xs, int TNB,
    const float* __restrict__ Wi,
    float* __restrict__ pre,
    int jquad, int dir, int t0f, int t0b, int s0, int s1, int tid)
{
    int wv = tid >> 6, l = tid & 63;
    int jb = jquad * 4 + wv;             // jblk 0..39 (38,39 -> dead rows, guarded)
    int lo5 = l & 31, hi5 = l >> 5;

    short8 aH2[NKS], aL2[NKS];
    {
        int g = lo5 & 3, uo = lo5 >> 2;
        int jrow = jb * 8 + uo;
        bool jok = jrow < 300;
        const float* wr = Wi + ((size_t)g * 300 + (jok ? jrow : 0)) * KMAXW;
#pragma unroll
        for (int ks = 0; ks < NKS; ++ks) {
            short8 vh, vl;
#pragma unroll
            for (int e = 0; e < 8; ++e) {
                int u = ks * 16 + hi5 * 8 + e;
                bool valid; int cc;
                if (KMAXW == 600) { valid = jok && ((u < 300) || (u >= 304 && u < 604)); cc = (u < 300) ? u : u - 4; }
                else              { valid = jok && (u < 300); cc = u; }
                float w = valid ? wr[cc] : 0.0f;
                u16 hb = f2bf(w);
                vh[e] = (short)hb;
                vl[e] = (short)f2bf(w - bf2f(hb));
            }
            aH2[ks] = vh; aL2[ks] = vl;
        }
    }

    for (int s = s0; s < s1; ++s) {
        int t = dir ? (t0b - s) : (t0f + s);
        const u16* bt = xs + ((size_t)t * TNB * 64) * 16;
        float* po = pre + (size_t)s * (G4 * 64);
#pragma unroll
        for (int bh2 = 0; bh2 < 2; ++bh2) {
            int bcol = bh2 * 32 + lo5;
            f32x16 aA = zero16(), aB = zero16(), aC = zero16();
#pragma unroll
            for (int ks = 0; ks < NKS; ++ks) {
                const u16* gp = bt + ((size_t)(2 * ks + hi5) * 64 + bcol) * 16;
                short8 bhv = *(const short8*)gp;
                short8 blv = *(const short8*)(gp + 8);
                aA = MF32(aH2[ks], bhv, aA);
                aB = MF32(aL2[ks], bhv, aB);
                aC = MF32(aH2[ks], blv, aC);
            }
#pragma unroll
            for (int r = 0; r < 16; ++r) {
                int m = (r & 3) + 8 * (r >> 2) + 4 * hi5;
                int gg = m & 3, u2 = m >> 2;
                int jr = jb * 8 + u2;
                if (jr < 300)
                    po[(gg * 300 + jr) * 64 + bcol] = aA[r] + aB[r] + aC[r];
            }
        }
    }
}

// ---------- standalone pregemm v3 (chunk 0 of each layer) ----------
template<int NKS, int KMAXW>
__global__ __launch_bounds__(256, 1) void k_pregemm3(
    const u16* __restrict__ xs, int TNB,
    const float* __restrict__ WiF, const float* __restrict__ WiB,
    float* __restrict__ preF, float* __restrict__ preB,
    int t0f, int t0b, int NSL, int C)
{
    int bx = blockIdx.x;
    int u = bx / NSL, sl = bx - u * NSL;
    int dir = u & 1, jquad = u >> 1;
    int s0 = sl * SSTEP, s1 = min(s0 + SSTEP, C);
    pregemm3_role<NKS, KMAXW>(xs, TNB, dir ? WiB : WiF,
        dir ? preB : preF, jquad, dir, t0f, t0b, s0, s1, threadIdx.x);
}

// ---------- lstm role: r3-proven (sharded poll + LDS combine); bias added here ----------
template<int MODE>
__device__ __forceinline__ void lstm_role(
    const float* __restrict__ preF, const float* __restrict__ preB,
    const float* __restrict__ WhF, const float* __restrict__ WhB,
    const float* __restrict__ biF, const float* __restrict__ bhF,
    const float* __restrict__ biB, const float* __restrict__ bhB,
    u16* __restrict__ hx, float* __restrict__ cbuf,
    float* __restrict__ xs2, u16* __restrict__ xs1,
    int t0f, int t0b, int C, int first,
    unsigned* __restrict__ flags,
    volatile unsigned* wgprog,
    int bid, int tid)
{
    __builtin_amdgcn_s_setprio(1);
    int dir = bid & 1, idx = bid >> 1;   // idx 0..37
    const float* pre = dir ? preB : preF;
    const float* Wh  = dir ? WhB : WhF;
    const float* biL = dir ? biB : biF;
    const float* bhL = dir ? bhB : bhF;
    u16* hxd = hx + (size_t)dir * 2 * HXE;
    float* cb = cbuf + (size_t)dir * 300 * 64;
    unsigned* flg = flags + (size_t)dir * FLGDIR;
    int w = tid >> 6, l = tid & 63;
    int hh = l >> 4, kbx = l >> 4;
    int bcol = w * 16 + (l & 15);
    int j0 = idx * 8;
    int ju0 = j0 + hh, ju1 = j0 + 4 + hh;
    int jc0 = min(ju0, 299), jc1 = min(ju1, 299);
    bool jv0 = ju0 < 300, jv1 = ju1 < 300;

    unsigned* myflag = flg + (size_t)(idx * 4 + w) * FLGS;
    const unsigned* shardp = flg + (size_t)(w * 38 + min(l, 37)) * FLGS;
    bool shact = l < 38;

    if (l == 0) wgprog[w] = 0;
    __syncthreads();

    // A fragments (2 stripes x hi/lo), preloaded once
    short8 aH[2][NKT], aL[2][NKT];
    {
        int r = l & 15;
        int g = r & 3, uo = r >> 2;
#pragma unroll
        for (int q = 0; q < 2; ++q) {
            int jr = j0 + q * 4 + uo;
            const float* wr = Wh + ((size_t)g * 300 + min(jr, 299)) * 300;
            bool jvr = jr < 300;
#pragma unroll
            for (int kt = 0; kt < NKT; ++kt) {
                short8 vh, vl;
#pragma unroll
                for (int e = 0; e < 8; ++e) {
                    int k = kt * 32 + kbx * 8 + e;
                    float wv = (jvr && k < 300) ? wr[k] : 0.0f;
                    u16 hb = f2bf(wv);
                    vh[e] = (short)hb;
                    vl[e] = (short)f2bf(wv - bf2f(hb));
                }
                aH[q][kt] = vh; aL[q][kt] = vl;
            }
        }
    }
    float c0 = first ? 0.0f : cb[(size_t)jc0 * 64 + bcol];
    float c1 = first ? 0.0f : cb[(size_t)jc1 * 64 + bcol];

    float bias0[4], bias1[4];
#pragma unroll
    for (int g = 0; g < 4; ++g) {
        bias0[g] = biL[g * 300 + jc0] + bhL[g * 300 + jc0];
        bias1[g] = biL[g * 300 + jc1] + bhL[g * 300 + jc1];
    }

    float p0[4], p1[4];
#pragma unroll
    for (int g = 0; g < 4; ++g) {
        p0[g] = pre[((size_t)g * 300 + jc0) * 64 + bcol] + bias0[g];
        p1[g] = pre[((size_t)g * 300 + jc1) * 64 + bcol] + bias1[g];
    }

    int pp = 0;
    for (int s = 0; s < C; ++s) {
        f32x4 aA0 = {0.f,0.f,0.f,0.f}, aB0 = {0.f,0.f,0.f,0.f}, aC0 = {0.f,0.f,0.f,0.f};
        f32x4 aA1 = {0.f,0.f,0.f,0.f}, aB1 = {0.f,0.f,0.f,0.f}, aC1 = {0.f,0.f,0.f,0.f};
        if (!(first && s == 0)) {
            const u16* hxr = hxd + (size_t)pp * HXE;
            i32x4 bh[NKT], bl[NKT];
#pragma unroll
            for (int kt = 0; kt < NKT; ++kt) {
                const u16* gp = hxr + (size_t)(4 * kt + kbx) * 1024 + (size_t)bcol * 8;
                bh[kt] = ld_cc_x4(gp);
            }
#pragma unroll
            for (int kt = 0; kt < NKT; ++kt) {
                const u16* gp = hxr + (size_t)(4 * kt + kbx) * 1024 + (size_t)bcol * 8;
                bl[kt] = ld_cc_x4(gp + 512);
            }
            asm volatile("s_waitcnt vmcnt(10)" ::: "memory");
            __builtin_amdgcn_sched_barrier(0);
#pragma unroll
            for (int kt = 0; kt < NKT; ++kt) {
                short8 bhv = __builtin_bit_cast(short8, bh[kt]);
                aA0 = MF(aH[0][kt], bhv, aA0);
                aB0 = MF(aL[0][kt], bhv, aB0);
                aA1 = MF(aH[1][kt], bhv, aA1);
                aB1 = MF(aL[1][kt], bhv, aB1);
            }
            wait_vm0();
            __builtin_amdgcn_sched_barrier(0);
#pragma unroll
            for (int kt = 0; kt < NKT; ++kt) {
                short8 blv = __builtin_bit_cast(short8, bl[kt]);
                aC0 = MF(aH[0][kt], blv, aC0);
                aC1 = MF(aH[1][kt], blv, aC1);
            }
        }
        float hv0, hv1;
        {
            float gi = sigf(aA0[0] + aB0[0] + aC0[0] + p0[0]);
            float gf = sigf(aA0[1] + aB0[1] + aC0[1] + p0[1]);
            float gg = tanhf(aA0[2] + aB0[2] + aC0[2] + p0[2]);
            float go = sigf(aA0[3] + aB0[3] + aC0[3] + p0[3]);
            c0 = gf * c0 + gi * gg;
            hv0 = go * tanhf(c0);
            if (!jv0) hv0 = 0.0f;
        }
        {
            float gi = sigf(aA1[0] + aB1[0] + aC1[0] + p1[0]);
            float gf = sigf(aA1[1] + aB1[1] + aC1[1] + p1[1]);
            float gg = tanhf(aA1[2] + aB1[2] + aC1[2] + p1[2]);
            float go = sigf(aA1[3] + aB1[3] + aC1[3] + p1[3]);
            c1 = gf * c1 + gi * gg;
            hv1 = go * tanhf(c1);
            if (!jv1) hv1 = 0.0f;
        }
        u16 hb0 = f2bf(hv0);
        unsigned pk0 = (unsigned)hb0 | ((unsigned)f2bf(hv0 - bf2f(hb0)) << 16);
        u16 hb1 = f2bf(hv1);
        unsigned pk1 = (unsigned)hb1 | ((unsigned)f2bf(hv1 - bf2f(hb1)) << 16);
        int ls = l & 15;
        unsigned a0 = __shfl(pk0, ls), a1 = __shfl(pk0, ls + 16), a2 = __shfl(pk0, ls + 32), a3 = __shfl(pk0, ls + 48);
        unsigned b0 = __shfl(pk1, ls), b1 = __shfl(pk1, ls + 16), b2 = __shfl(pk1, ls + 32), b3 = __shfl(pk1, ls + 48);
        i32x4 hi4 = {(int)((a0 & 0xffffu) | (a1 << 16)), (int)((a2 & 0xffffu) | (a3 << 16)),
                     (int)((b0 & 0xffffu) | (b1 << 16)), (int)((b2 & 0xffffu) | (b3 << 16))};
        i32x4 lo4 = {(int)((a0 >> 16) | (a1 & 0xffff0000u)), (int)((a2 >> 16) | (a3 & 0xffff0000u)),
                     (int)((b0 >> 16) | (b1 & 0xffff0000u)), (int)((b2 >> 16) | (b3 & 0xffff0000u))};
        int t = dir ? (t0b - s) : (t0f + s);
        if (l < 16) {
            int b = w * 16 + l;
            u16* hxw = hxd + (size_t)(pp ^ 1) * HXE + (size_t)idx * 1024 + (size_t)b * 8;
            st_cc_x4(hxw, hi4);
            st_cc_x4(hxw + 512, lo4);
        }
        wait_vm0();
        if (l == 0) st_cc_b32(myflag, (unsigned)(s + 1));
        if (MODE == 0) {
            if (jv0) xs2[((size_t)t * 600 + dir * 300 + ju0) * 64 + bcol] = hv0;
            if (jv1) xs2[((size_t)t * 600 + dir * 300 + ju1) * 64 + bcol] = hv1;
        } else if (l < 16) {
            int b = w * 16 + l;
            u16* xd = xs1 + (((size_t)t * 80 + dir * 38 + idx) * 64 + b) * 16;
            *(i32x4*)xd       = hi4;
            *(i32x4*)(xd + 8) = lo4;
        }
        if (s + 1 < C) {
#pragma unroll
            for (int g = 0; g < 4; ++g) {
                p0[g] = pre[((size_t)(s + 1) * G4 + (size_t)g * 300 + jc0) * 64 + bcol] + bias0[g];
                p1[g] = pre[((size_t)(s + 1) * G4 + (size_t)g * 300 + jc1) * 64 + bcol] + bias1[g];
            }
            unsigned tgt = (unsigned)(s + 1);
            unsigned ok;
            do {
                unsigned v = tgt;
                if (shact) v = ld_cc_b32(shardp);
                ok = (v >= tgt) ? 1u : 0u;
            } while (!__all(ok));
            if (l == 0) wgprog[w] = tgt;
            while (!(wgprog[0] >= tgt && wgprog[1] >= tgt &&
                     wgprog[2] >= tgt && wgprog[3] >= tgt)) {
                __builtin_amdgcn_s_sleep(1);
            }
        }
        pp ^= 1;
    }
    if (jv0) cb[(size_t)jc0 * 64 + bcol] = c0;
    if (jv1) cb[(size_t)jc1 * 64 + bcol] = c1;
}

// ---------- fused chunk kernel: 76 lstm WGs + 80 pregemm-v3 companions ----------
template<int NKS, int KMAXW, int MODE>
__global__ __launch_bounds__(256, 1) void k_chunk(
    const u16* __restrict__ xsN, int TNB,
    const float* __restrict__ WiF, const float* __restrict__ WiB,
    float* __restrict__ preNF, float* __restrict__ preNB,
    int t0fN, int t0bN, int do_pre, int CN, int NSLc,
    const float* __restrict__ preF, const float* __restrict__ preB,
    const float* __restrict__ WhF, const float* __restrict__ WhB,
    const float* __restrict__ biF, const float* __restrict__ bhF,
    const float* __restrict__ biB, const float* __restrict__ bhB,
    u16* __restrict__ hx, float* __restrict__ cbuf,
    float* __restrict__ xs2, u16* __restrict__ xs1,
    int t0f, int t0b, int C, int first,
    unsigned* __restrict__ flags)
{
    __shared__ unsigned wgprog[4];
    int bid = blockIdx.x;
    if (bid < 2 * NWGD) {
        lstm_role<MODE>(preF, preB, WhF, WhB, biF, bhF, biB, bhB, hx, cbuf,
                        xs2, xs1, t0f, t0b, C, first, flags, wgprog,
                        bid, threadIdx.x);
    } else if (do_pre) {
        int p = bid - 2 * NWGD;          // 0..79
        if (p < 20 * NSLc) {
            int u = p / NSLc, sl = p - u * NSLc;
            int dir = u & 1, jquad = u >> 1;
            int s0 = sl * SSTEP, s1 = min(s0 + SSTEP, CN);
            pregemm3_role<NKS, KMAXW>(xsN, TNB, dir ? WiB : WiF,
                dir ? preNB : preNF, jquad, dir, t0fN, t0bN, s0, s1, threadIdx.x);
        }
    }
}

// ---------- output projection: feats[t][g][b] ----------
__global__ __launch_bounds__(256) void k_feats(
    const float* __restrict__ xs2, const float* __restrict__ Wout,
    const float* __restrict__ bout, float* __restrict__ feats)
{
    int t = blockIdx.x;
    int tid = threadIdx.x;
    int b = tid & 63, g0 = tid >> 6;
    const float* xa = xs2 + (size_t)t * 600 * 64 + b;
    for (int g = g0; g < NTAG; g += 4) {
        float acc = bout[g];
        const float* wr = Wout + (size_t)g * 600;
#pragma unroll 4
        for (int k = 0; k < 600; ++k) acc += wr[k] * xa[(size_t)k * 64];
        feats[((size_t)t * NTAG + g) * 64 + b] = acc;
    }
}

// ---------- Viterbi ----------
__global__ __launch_bounds__(256) void k_viterbi(
    const float* __restrict__ feats, const float* __restrict__ trans,
    float* __restrict__ out)
{
    __shared__ unsigned char bp[4][T_SEQ * NTAG];
    int tid = threadIdx.x;
    int wv = tid >> 6, lane = tid & 63;
    int b = blockIdx.x * 4 + wv;
    int i = (lane < NTAG) ? lane : 0;
    bool act = lane < NTAG;
    float trow[NTAG];
#pragma unroll
    for (int j = 0; j < NTAG; ++j) trow[j] = trans[i * NTAG + j];
    float fv = (lane == TAG_START) ? 0.0f : NEGV;
    for (int t = 0; t < T_SEQ; ++t) {
        float m = -3.0e38f; int arg = 0;
#pragma unroll
        for (int j = 0; j < NTAG; ++j) {
            float fvj = __shfl(fv, j, 64);
            float sc = fvj + trow[j];
            if (sc > m) { m = sc; arg = j; }
        }
        float ft = feats[((size_t)t * NTAG + i) * 64 + b];
        fv = m + ft;
        if (act) bp[wv][t * NTAG + lane] = (unsigned char)arg;
    }
    float term = act ? (fv + trans[TAG_STOP * NTAG + i]) : -3.0e38f;
    int bi_ = lane;
#pragma unroll
    for (int off = 32; off >= 1; off >>= 1) {
        float ov = __shfl_xor(term, off, 64);
        int oi = __shfl_xor(bi_, off, 64);
        if (ov > term || (ov == term && oi < bi_)) { term = ov; bi_ = oi; }
    }
    if (lane == 0) {
        out[b] = term;
        int tag = bi_;
        float* po = out + 64 + (size_t)b * T_SEQ;
        for (int t = T_SEQ - 1; t >= 0; --t) {
            po[t] = (float)tag;
            tag = bp[wv][t * NTAG + tag];
        }
    }
}

extern "C" void kernel_launch(void* const* d_in, const int* in_sizes, int n_in,
                              void* d_out, int out_size, void* d_ws, size_t ws_size,
                              hipStream_t stream)
{
    (void)in_sizes; (void)n_in; (void)out_size;
    const int*   x     = (const int*)d_in[0];
    const float* emb   = (const float*)d_in[1];
    const float* Wout  = (const float*)d_in[2];
    const float* bout  = (const float*)d_in[3];
    const float* trans = (const float*)d_in[4];

    float* ws = (float*)d_ws;
    const size_t XS2F = (size_t)T_SEQ * 600 * NBATCH;          // f32
    const size_t XS1U = (size_t)T_SEQ * 80 * 64 * 16;          // u16
    const size_t FEA  = (size_t)T_SEQ * NTAG * NBATCH;

    float* xs2 = ws;                          // layer-1 f32 output (aliases xs0 blocks)
    u16* xs0 = (u16*)ws;                      // [T][40][64][2][8]
    u16* xs1 = (u16*)(ws + XS2F);             // [T][80][64][2][8]
    float* featB = (float*)(xs1 + XS1U);
    float* cB = featB + FEA;                  // 2*300*64
    u16* hxB = (u16*)(cB + 2 * 300 * 64);     // 4*HXE
    unsigned* flagsB = (unsigned*)(hxB + 4 * HXE);   // 64 slots * 2 dirs * FLGDIR
    unsigned* padB = flagsB + 64ULL * 2 * FLGDIR;    // layout hole kept (16 u32)
    float* preBase = (float*)(padB + 16);
    size_t fixedBytes = (size_t)((char*)preBase - (char*)ws);

    // two ping-pong pre slots; each slot = 2 dirs x Cmax*G4*64 floats
    int Cmax = 512;
    while (Cmax > 16 && fixedBytes + 16ULL * Cmax * G4 * NBATCH > ws_size) Cmax >>= 1;
    size_t Q = (size_t)Cmax * G4 * NBATCH;    // floats per dir buf
    size_t slotF = 2 * Q;
    float* preS[2] = { preBase, preBase + slotF };

    // chunk schedule: small first chunk shrinks the first exposed pregemm
    int sizes[40], off[41], nch = 0;
    {
        int rem = T_SEQ;
        int f = (Cmax >= 64) ? 32 : Cmax;
        sizes[nch++] = f; rem -= f;
        while (rem > 0) { int s = rem < Cmax ? rem : Cmax; sizes[nch++] = s; rem -= s; }
        off[0] = 0;
        for (int i = 0; i < nch; ++i) off[i + 1] = off[i] + sizes[i];
    }

    (void)hipMemsetAsync(hxB, 0,
        4 * HXE * sizeof(u16) + (64ULL * 2 * FLGDIR) * sizeof(unsigned), stream);
    k_gather<<<T_SEQ, 256, 0, stream>>>(x, emb, xs0);
    k_zpad<<<T_SEQ, 256, 0, stream>>>(xs1);

    for (int layer = 0; layer < 2; ++layer) {
        int base = 5 + layer * 8;
        const float* WiF = (const float*)d_in[base + 0];
        const float* WhF = (const float*)d_in[base + 1];
        const float* biF = (const float*)d_in[base + 2];
        const float* bhF = (const float*)d_in[base + 3];
        const float* WiB = (const float*)d_in[base + 4];
        const float* WhB = (const float*)d_in[base + 5];
        const float* biB = (const float*)d_in[base + 6];
        const float* bhB = (const float*)d_in[base + 7];
        const u16* xsL = (layer == 0) ? xs0 : xs1;
        int TNB = (layer == 0) ? 40 : 80;

        // chunk-0 pregemm (slot 0)
        {
            int NSL0 = (sizes[0] + SSTEP - 1) / SSTEP;
            if (layer == 0)
                k_pregemm3<20, 300><<<20 * NSL0, 256, 0, stream>>>(
                    xsL, TNB, WiF, WiB, preS[0], preS[0] + Q, 0, T_SEQ - 1, NSL0, sizes[0]);
            else
                k_pregemm3<40, 600><<<20 * NSL0, 256, 0, stream>>>(
                    xsL, TNB, WiF, WiB, preS[0], preS[0] + Q, 0, T_SEQ - 1, NSL0, sizes[0]);
        }

        for (int ci = 0; ci < nch; ++ci) {
            int cur = ci & 1, nxt = cur ^ 1;
            int t0f = off[ci], t0b = (T_SEQ - 1) - off[ci];
            int do_pre = (ci + 1 < nch) ? 1 : 0;
            int CN = do_pre ? sizes[ci + 1] : 0;
            int NSLc = do_pre ? (CN + SSTEP - 1) / SSTEP : 1;
            int t0fN = off[ci + 1], t0bN = (T_SEQ - 1) - off[ci + 1];
            int slot = layer * 32 + ci;
            unsigned* flags = flagsB + (size_t)slot * 2 * FLGDIR;
            float* pc = preS[cur];
            float* pn = preS[nxt];
            if (layer == 0)
                k_chunk<20, 300, 1><<<2 * NWGD + NCOMP, 256, 0, stream>>>(
                    xsL, TNB, WiF, WiB, pn, pn + Q, t0fN, t0bN, do_pre, CN, NSLc,
                    pc, pc + Q, WhF, WhB, biF, bhF, biB, bhB, hxB, cB,
                    xs2, xs1, t0f, t0b, sizes[ci], (ci == 0) ? 1 : 0, flags);
            else
                k_chunk<40, 600, 0><<<2 * NWGD + NCOMP, 256, 0, stream>>>(
                    xsL, TNB, WiF, WiB, pn, pn + Q, t0fN, t0bN, do_pre, CN, NSLc,
                    pc, pc + Q, WhF, WhB, biF, bhF, biB, bhB, hxB, cB,
                    xs2, xs1, t0f, t0b, sizes[ci], (ci == 0) ? 1 : 0, flags);
        }
    }
    k_feats<<<T_SEQ, 256, 0, stream>>>(xs2, Wout, bout, featB);
    k_viterbi<<<16, 256, 0, stream>>>(featB, trans, (float*)d_out);
}

// Round 10
// 6410.500 us; speedup vs baseline: 1.4236x; 1.1017x over previous
//
#include <hip/hip_runtime.h>
#include <hip/hip_bf16.h>

#define T_SEQ 512
#define NBATCH 64
#define HID 300
#define G4 1200
#define NTAG 11
#define TAG_START 9
#define TAG_STOP 10
#define NEGV -10000.0f
#define NWGD 38             // lstm WGs per direction, 8 hidden units (= 1 kblock) each
#define NKT 10              // k-tiles of 32 (K padded 300->320)
#define HXE (40*2*64*8)     // u16 per (dir,pp) hx buffer: 40 kblocks x {hi,lo} x 64 b x 8
#define FLGS 16             // u32 stride between flags (64B slots)
#define FLGN 152            // flags per dir = 38 WGs x 4 waves
#define FLGDIR (FLGN*FLGS)
#define SSTEP 16            // pregemm timestep slice
#define NCOMP 80            // companion WGs in fused kernel

typedef unsigned short u16;
using short8 = __attribute__((ext_vector_type(8))) short;
using f32x4  = __attribute__((ext_vector_type(4))) float;
using f32x16 = __attribute__((ext_vector_type(16))) float;
using i32x4  = __attribute__((ext_vector_type(4))) int;

#define MF(a, b, c)   __builtin_amdgcn_mfma_f32_16x16x32_bf16((a), (b), (c), 0, 0, 0)
#define MF32(a, b, c) __builtin_amdgcn_mfma_f32_32x32x16_bf16((a), (b), (c), 0, 0, 0)

__device__ __forceinline__ float sigf(float x) { return 1.0f / (1.0f + expf(-x)); }

__device__ __forceinline__ u16 f2bf(float x) {
    unsigned u = __float_as_uint(x);
    unsigned r = (u + 0x7FFFu + ((u >> 16) & 1u)) >> 16;   // RNE
    return (u16)r;
}
__device__ __forceinline__ float bf2f(u16 h) {
    return __uint_as_float((unsigned)h << 16);
}
__device__ __forceinline__ f32x16 zero16() {
    f32x16 z = {0.f,0.f,0.f,0.f,0.f,0.f,0.f,0.f,0.f,0.f,0.f,0.f,0.f,0.f,0.f,0.f};
    return z;
}

// ---- LLC-coherent (device scope) helpers: sc0 sc1 ----
__device__ __forceinline__ i32x4 ld_cc_x4(const u16* p) {
    i32x4 r;
    asm volatile("global_load_dwordx4 %0, %1, off sc0 sc1" : "=v"(r) : "v"(p) : "memory");
    return r;
}
__device__ __forceinline__ unsigned ld_cc_b32(const unsigned* p) {
    unsigned r;
    asm volatile("global_load_dword %0, %1, off sc0 sc1\n\t"
                 "s_waitcnt vmcnt(0)" : "=v"(r) : "v"(p) : "memory");
    return r;
}
__device__ __forceinline__ void st_cc_x4(u16* p, i32x4 v) {
    asm volatile("global_store_dwordx4 %0, %1, off sc0 sc1" :: "v"(p), "v"(v) : "memory");
}
__device__ __forceinline__ void st_cc_b32(unsigned* p, unsigned v) {
    asm volatile("global_store_dword %0, %1, off sc0 sc1" :: "v"(p), "v"(v) : "memory");
}
__device__ __forceinline__ void wait_vm0() {
    asm volatile("s_waitcnt vmcnt(0)" ::: "memory");
}

// ---------- embedding gather -> block layout xs0[t][40][64][2][8] (hi8|lo8 u16) ----------
__global__ __launch_bounds__(256) void k_gather(const int* __restrict__ x,
                                                const float* __restrict__ emb,
                                                u16* __restrict__ xs0)
{
    int t = blockIdx.x;
    __shared__ int rid[NBATCH];
    if (threadIdx.x < NBATCH) rid[threadIdx.x] = x[threadIdx.x * T_SEQ + t];
    __syncthreads();
    for (int o = threadIdx.x; o < 64 * 40; o += 256) {
        int b = o / 40, m8 = o - b * 40;
        unsigned hw[4], lw[4];
#pragma unroll
        for (int p = 0; p < 4; ++p) {
            int k0 = m8 * 8 + p * 2;
            float v0 = (k0 < 300)     ? emb[(size_t)rid[b] * 300 + k0]     : 0.0f;
            float v1 = (k0 + 1 < 300) ? emb[(size_t)rid[b] * 300 + k0 + 1] : 0.0f;
            u16 h0 = f2bf(v0), h1 = f2bf(v1);
            u16 l0 = f2bf(v0 - bf2f(h0)), l1 = f2bf(v1 - bf2f(h1));
            hw[p] = (unsigned)h0 | ((unsigned)h1 << 16);
            lw[p] = (unsigned)l0 | ((unsigned)l1 << 16);
        }
        u16* dst = xs0 + (((size_t)t * 40 + m8) * 64 + b) * 16;
        *(i32x4*)dst       = i32x4{(int)hw[0], (int)hw[1], (int)hw[2], (int)hw[3]};
        *(i32x4*)(dst + 8) = i32x4{(int)lw[0], (int)lw[1], (int)lw[2], (int)lw[3]};
    }
}

// ---------- zero xs1 pad blocks 76..79 ----------
__global__ __launch_bounds__(256) void k_zpad(u16* __restrict__ xs1)
{
    int t = blockIdx.x;
    i32x4* base = (i32x4*)(xs1 + (((size_t)t * 80 + 76) * 64) * 16);
    i32x4 z = {0, 0, 0, 0};
    for (int o = threadIdx.x; o < 4 * 64 * 2; o += 256) base[o] = z;
}

// ---------- pregemm v3-seg: 32x32x16 MFMA, 128 rows/WG, NKS=20 (register-fit) ----------
// Unit = (jquad, dir, seg). jb = jquad*4 + wave; 4 waves stream the SAME
// 40-block B window (L1/L2 dedup). Per-seg K window: B0 = seg*38 blocks,
// KOFF = seg*300 weight cols, validity u<300 (r7-proven; pads/overreads hit
// zero weights or zeroed pad blocks). NO bias here (lstm adds it).
// Fragment maps r7/r8-refcheck-proven: A row=l&31, k=(l>>5)*8+e; B col=l&31
// (+bhalf*32); C/D col=l&31, row=(r&3)+8*(r>>2)+4*(l>>5).
template<int KMAXW>
__device__ __forceinline__ void pregemm3_role(
    const u16* __restrict__ xs, int TNB,
    const float* __restrict__ Wi,
    float* __restrict__ pre,
    int jquad, int dir, int B0, int KOFF,
    int t0f, int t0b, int s0, int s1, int tid)
{
    const int NKS = 20;
    int wv = tid >> 6, l = tid & 63;
    int jb = jquad * 4 + wv;             // jblk 0..39 (38,39 dead rows, guarded)
    int lo5 = l & 31, hi5 = l >> 5;

    short8 aH2[NKS], aL2[NKS];
    {
        int g = lo5 & 3, uo = lo5 >> 2;
        int jrow = jb * 8 + uo;
        bool jok = jrow < 300;
        const float* wr = Wi + ((size_t)g * 300 + (jok ? jrow : 0)) * KMAXW + KOFF;
#pragma unroll
        for (int ks = 0; ks < NKS; ++ks) {
            short8 vh, vl;
#pragma unroll
            for (int e = 0; e < 8; ++e) {
                int u = ks * 16 + hi5 * 8 + e;
                float w = (jok && u < 300) ? wr[u] : 0.0f;
                u16 hb = f2bf(w);
                vh[e] = (short)hb;
                vl[e] = (short)f2bf(w - bf2f(hb));
            }
            aH2[ks] = vh; aL2[ks] = vl;
        }
    }

    for (int s = s0; s < s1; ++s) {
        int t = dir ? (t0b - s) : (t0f + s);
        const u16* bt = xs + (((size_t)t * TNB + B0) * 64) * 16;
        float* po = pre + (size_t)s * (G4 * 64);
#pragma unroll
        for (int bh2 = 0; bh2 < 2; ++bh2) {
            int bcol = bh2 * 32 + lo5;
            f32x16 aA = zero16(), aB = zero16(), aC = zero16();
#pragma unroll
            for (int ks = 0; ks < NKS; ++ks) {
                const u16* gp = bt + ((size_t)(2 * ks + hi5) * 64 + bcol) * 16;
                short8 bhv = *(const short8*)gp;
                short8 blv = *(const short8*)(gp + 8);
                aA = MF32(aH2[ks], bhv, aA);
                aB = MF32(aL2[ks], bhv, aB);
                aC = MF32(aH2[ks], blv, aC);
            }
#pragma unroll
            for (int r = 0; r < 16; ++r) {
                int m = (r & 3) + 8 * (r >> 2) + 4 * hi5;
                int gg = m & 3, u2 = m >> 2;
                int jr = jb * 8 + u2;
                if (jr < 300)
                    po[(gg * 300 + jr) * 64 + bcol] = aA[r] + aB[r] + aC[r];
            }
        }
    }
}

// ---------- standalone pregemm v3-seg (chunk 0 of each layer) ----------
// grid = NSEG*20 units x NSL slices; unit u: dir=u&1, rest=u>>1,
// seg = rest>=10, jquad = rest-seg*10. dst buf = pbase + (seg*2+dir)*Q.
template<int KMAXW>
__global__ __launch_bounds__(256, 1) void k_pregemm3(
    const u16* __restrict__ xs, int TNB,
    const float* __restrict__ WiF, const float* __restrict__ WiB,
    float* __restrict__ pbase, unsigned long long Q,
    int t0f, int t0b, int NSL, int C)
{
    int bx = blockIdx.x;
    int u = bx / NSL, sl = bx - u * NSL;
    int dir = u & 1, rest = u >> 1;
    int seg = (rest >= 10) ? 1 : 0;
    int jq = rest - seg * 10;
    int s0 = sl * SSTEP, s1 = min(s0 + SSTEP, C);
    pregemm3_role<KMAXW>(xs, TNB, dir ? WiB : WiF,
        pbase + (size_t)(seg * 2 + dir) * Q, jq, dir, seg * 38, seg * 300,
        t0f, t0b, s0, s1, threadIdx.x);
}

// ---------- lstm role: r3-proven sync; bias here; MODE=0 sums pre+pre2 ----------
template<int MODE>
__device__ __forceinline__ void lstm_role(
    const float* __restrict__ pc, unsigned long long Qc,
    const float* __restrict__ WhF, const float* __restrict__ WhB,
    const float* __restrict__ biF, const float* __restrict__ bhF,
    const float* __restrict__ biB, const float* __restrict__ bhB,
    u16* __restrict__ hx, float* __restrict__ cbuf,
    float* __restrict__ xs2, u16* __restrict__ xs1,
    int t0f, int t0b, int C, int first,
    unsigned* __restrict__ flags,
    volatile unsigned* wgprog,
    int bid, int tid)
{
    __builtin_amdgcn_s_setprio(1);
    int dir = bid & 1, idx = bid >> 1;   // idx 0..37
    const float* pre  = pc + (size_t)dir * Qc;
    const float* pre2 = pc + (size_t)(2 + dir) * Qc;   // MODE==0 only
    const float* Wh  = dir ? WhB : WhF;
    const float* biL = dir ? biB : biF;
    const float* bhL = dir ? bhB : bhF;
    u16* hxd = hx + (size_t)dir * 2 * HXE;
    float* cb = cbuf + (size_t)dir * 300 * 64;
    unsigned* flg = flags + (size_t)dir * FLGDIR;
    int w = tid >> 6, l = tid & 63;
    int hh = l >> 4, kbx = l >> 4;
    int bcol = w * 16 + (l & 15);
    int j0 = idx * 8;
    int ju0 = j0 + hh, ju1 = j0 + 4 + hh;
    int jc0 = min(ju0, 299), jc1 = min(ju1, 299);
    bool jv0 = ju0 < 300, jv1 = ju1 < 300;

    unsigned* myflag = flg + (size_t)(idx * 4 + w) * FLGS;
    const unsigned* shardp = flg + (size_t)(w * 38 + min(l, 37)) * FLGS;
    bool shact = l < 38;

    if (l == 0) wgprog[w] = 0;
    __syncthreads();

    // A fragments (2 stripes x hi/lo), preloaded once
    short8 aH[2][NKT], aL[2][NKT];
    {
        int r = l & 15;
        int g = r & 3, uo = r >> 2;
#pragma unroll
        for (int q = 0; q < 2; ++q) {
            int jr = j0 + q * 4 + uo;
            const float* wr = Wh + ((size_t)g * 300 + min(jr, 299)) * 300;
            bool jvr = jr < 300;
#pragma unroll
            for (int kt = 0; kt < NKT; ++kt) {
                short8 vh, vl;
#pragma unroll
                for (int e = 0; e < 8; ++e) {
                    int k = kt * 32 + kbx * 8 + e;
                    float wv = (jvr && k < 300) ? wr[k] : 0.0f;
                    u16 hb = f2bf(wv);
                    vh[e] = (short)hb;
                    vl[e] = (short)f2bf(wv - bf2f(hb));
                }
                aH[q][kt] = vh; aL[q][kt] = vl;
            }
        }
    }
    float c0 = first ? 0.0f : cb[(size_t)jc0 * 64 + bcol];
    float c1 = first ? 0.0f : cb[(size_t)jc1 * 64 + bcol];

    float bias0[4], bias1[4];
#pragma unroll
    for (int g = 0; g < 4; ++g) {
        bias0[g] = biL[g * 300 + jc0] + bhL[g * 300 + jc0];
        bias1[g] = biL[g * 300 + jc1] + bhL[g * 300 + jc1];
    }

    float p0[4], p1[4];
#pragma unroll
    for (int g = 0; g < 4; ++g) {
        size_t o0 = ((size_t)g * 300 + jc0) * 64 + bcol;
        size_t o1 = ((size_t)g * 300 + jc1) * 64 + bcol;
        p0[g] = pre[o0] + bias0[g];
        p1[g] = pre[o1] + bias1[g];
        if (MODE == 0) { p0[g] += pre2[o0]; p1[g] += pre2[o1]; }
    }

    int pp = 0;
    for (int s = 0; s < C; ++s) {
        f32x4 aA0 = {0.f,0.f,0.f,0.f}, aB0 = {0.f,0.f,0.f,0.f}, aC0 = {0.f,0.f,0.f,0.f};
        f32x4 aA1 = {0.f,0.f,0.f,0.f}, aB1 = {0.f,0.f,0.f,0.f}, aC1 = {0.f,0.f,0.f,0.f};
        if (!(first && s == 0)) {
            const u16* hxr = hxd + (size_t)pp * HXE;
            i32x4 bh[NKT], bl[NKT];
#pragma unroll
            for (int kt = 0; kt < NKT; ++kt) {
                const u16* gp = hxr + (size_t)(4 * kt + kbx) * 1024 + (size_t)bcol * 8;
                bh[kt] = ld_cc_x4(gp);
            }
#pragma unroll
            for (int kt = 0; kt < NKT; ++kt) {
                const u16* gp = hxr + (size_t)(4 * kt + kbx) * 1024 + (size_t)bcol * 8;
                bl[kt] = ld_cc_x4(gp + 512);
            }
            asm volatile("s_waitcnt vmcnt(10)" ::: "memory");
            __builtin_amdgcn_sched_barrier(0);
#pragma unroll
            for (int kt = 0; kt < NKT; ++kt) {
                short8 bhv = __builtin_bit_cast(short8, bh[kt]);
                aA0 = MF(aH[0][kt], bhv, aA0);
                aB0 = MF(aL[0][kt], bhv, aB0);
                aA1 = MF(aH[1][kt], bhv, aA1);
                aB1 = MF(aL[1][kt], bhv, aB1);
            }
            wait_vm0();
            __builtin_amdgcn_sched_barrier(0);
#pragma unroll
            for (int kt = 0; kt < NKT; ++kt) {
                short8 blv = __builtin_bit_cast(short8, bl[kt]);
                aC0 = MF(aH[0][kt], blv, aC0);
                aC1 = MF(aH[1][kt], blv, aC1);
            }
        }
        float hv0, hv1;
        {
            float gi = sigf(aA0[0] + aB0[0] + aC0[0] + p0[0]);
            float gf = sigf(aA0[1] + aB0[1] + aC0[1] + p0[1]);
            float gg = tanhf(aA0[2] + aB0[2] + aC0[2] + p0[2]);
            float go = sigf(aA0[3] + aB0[3] + aC0[3] + p0[3]);
            c0 = gf * c0 + gi * gg;
            hv0 = go * tanhf(c0);
            if (!jv0) hv0 = 0.0f;
        }
        {
            float gi = sigf(aA1[0] + aB1[0] + aC1[0] + p1[0]);
            float gf = sigf(aA1[1] + aB1[1] + aC1[1] + p1[1]);
            float gg = tanhf(aA1[2] + aB1[2] + aC1[2] + p1[2]);
            float go = sigf(aA1[3] + aB1[3] + aC1[3] + p1[3]);
            c1 = gf * c1 + gi * gg;
            hv1 = go * tanhf(c1);
            if (!jv1) hv1 = 0.0f;
        }
        u16 hb0 = f2bf(hv0);
        unsigned pk0 = (unsigned)hb0 | ((unsigned)f2bf(hv0 - bf2f(hb0)) << 16);
        u16 hb1 = f2bf(hv1);
        unsigned pk1 = (unsigned)hb1 | ((unsigned)f2bf(hv1 - bf2f(hb1)) << 16);
        int ls = l & 15;
        unsigned a0 = __shfl(pk0, ls), a1 = __shfl(pk0, ls + 16), a2 = __shfl(pk0, ls + 32), a3 = __shfl(pk0, ls + 48);
        unsigned b0 = __shfl(pk1, ls), b1 = __shfl(pk1, ls + 16), b2 = __shfl(pk1, ls + 32), b3 = __shfl(pk1, ls + 48);
        i32x4 hi4 = {(int)((a0 & 0xffffu) | (a1 << 16)), (int)((a2 & 0xffffu) | (a3 << 16)),
                     (int)((b0 & 0xffffu) | (b1 << 16)), (int)((b2 & 0xffffu) | (b3 << 16))};
        i32x4 lo4 = {(int)((a0 >> 16) | (a1 & 0xffff0000u)), (int)((a2 >> 16) | (a3 & 0xffff0000u)),
                     (int)((b0 >> 16) | (b1 & 0xffff0000u)), (int)((b2 >> 16) | (b3 & 0xffff0000u))};
        int t = dir ? (t0b - s) : (t0f + s);
        if (l < 16) {
            int b = w * 16 + l;
            u16* hxw = hxd + (size_t)(pp ^ 1) * HXE + (size_t)idx * 1024 + (size_t)b * 8;
            st_cc_x4(hxw, hi4);
            st_cc_x4(hxw + 512, lo4);
        }
        wait_vm0();
        if (l == 0) st_cc_b32(myflag, (unsigned)(s + 1));
        if (MODE == 0) {
            if (jv0) xs2[((size_t)t * 600 + dir * 300 + ju0) * 64 + bcol] = hv0;
            if (jv1) xs2[((size_t)t * 600 + dir * 300 + ju1) * 64 + bcol] = hv1;
        } else if (l < 16) {
            int b = w * 16 + l;
            u16* xd = xs1 + (((size_t)t * 80 + dir * 38 + idx) * 64 + b) * 16;
            *(i32x4*)xd       = hi4;
            *(i32x4*)(xd + 8) = lo4;
        }
        if (s + 1 < C) {
#pragma unroll
            for (int g = 0; g < 4; ++g) {
                size_t o0 = ((size_t)(s + 1) * G4 + (size_t)g * 300 + jc0) * 64 + bcol;
                size_t o1 = ((size_t)(s + 1) * G4 + (size_t)g * 300 + jc1) * 64 + bcol;
                p0[g] = pre[o0] + bias0[g];
                p1[g] = pre[o1] + bias1[g];
                if (MODE == 0) { p0[g] += pre2[o0]; p1[g] += pre2[o1]; }
            }
            unsigned tgt = (unsigned)(s + 1);
            unsigned ok;
            do {
                unsigned v = tgt;
                if (shact) v = ld_cc_b32(shardp);
                ok = (v >= tgt) ? 1u : 0u;
            } while (!__all(ok));
            if (l == 0) wgprog[w] = tgt;
            while (!(wgprog[0] >= tgt && wgprog[1] >= tgt &&
                     wgprog[2] >= tgt && wgprog[3] >= tgt)) {
                __builtin_amdgcn_s_sleep(1);
            }
        }
        pp ^= 1;
    }
    if (jv0) cb[(size_t)jc0 * 64 + bcol] = c0;
    if (jv1) cb[(size_t)jc1 * 64 + bcol] = c1;
}

// ---------- fused chunk kernel: 76 lstm WGs + up to 80 pregemm-v3-seg companions ----------
// MODE=1 (layer0): 20 units (seg 0 only); MODE=0 (layer1): 40 units (2 segs).
template<int KMAXW, int MODE>
__global__ __launch_bounds__(256, 1) void k_chunk(
    const u16* __restrict__ xsN, int TNB,
    const float* __restrict__ WiF, const float* __restrict__ WiB,
    float* __restrict__ pn, unsigned long long Qn,
    int t0fN, int t0bN, int do_pre, int CN, int NSLc,
    const float* __restrict__ pc, unsigned long long Qc,
    const float* __restrict__ WhF, const float* __restrict__ WhB,
    const float* __restrict__ biF, const float* __restrict__ bhF,
    const float* __restrict__ biB, const float* __restrict__ bhB,
    u16* __restrict__ hx, float* __restrict__ cbuf,
    float* __restrict__ xs2, u16* __restrict__ xs1,
    int t0f, int t0b, int C, int first,
    unsigned* __restrict__ flags)
{
    __shared__ unsigned wgprog[4];
    int bid = blockIdx.x;
    if (bid < 2 * NWGD) {
        lstm_role<MODE>(pc, Qc, WhF, WhB, biF, bhF, biB, bhB, hx, cbuf,
                        xs2, xs1, t0f, t0b, C, first, flags, wgprog,
                        bid, threadIdx.x);
    } else if (do_pre) {
        const int NUNITS = (MODE == 0) ? 40 : 20;
        int p = bid - 2 * NWGD;          // 0..NCOMP-1
        if (p < NUNITS * NSLc) {
            int u = p / NSLc, sl = p - u * NSLc;
            int dir = u & 1, rest = u >> 1;
            int seg = (rest >= 10) ? 1 : 0;
            int jq = rest - seg * 10;
            int s0 = sl * SSTEP, s1 = min(s0 + SSTEP, CN);
            pregemm3_role<KMAXW>(xsN, TNB, dir ? WiB : WiF,
                pn + (size_t)(seg * 2 + dir) * Qn, jq, dir, seg * 38, seg * 300,
                t0fN, t0bN, s0, s1, threadIdx.x);
        }
    }
}

// ---------- output projection: feats[t][g][b] ----------
__global__ __launch_bounds__(256) void k_feats(
    const float* __restrict__ xs2, const float* __restrict__ Wout,
    const float* __restrict__ bout, float* __restrict__ feats)
{
    int t = blockIdx.x;
    int tid = threadIdx.x;
    int b = tid & 63, g0 = tid >> 6;
    const float* xa = xs2 + (size_t)t * 600 * 64 + b;
    for (int g = g0; g < NTAG; g += 4) {
        float acc = bout[g];
        const float* wr = Wout + (size_t)g * 600;
#pragma unroll 4
        for (int k = 0; k < 600; ++k) acc += wr[k] * xa[(size_t)k * 64];
        feats[((size_t)t * NTAG + g) * 64 + b] = acc;
    }
}

// ---------- Viterbi ----------
__global__ __launch_bounds__(256) void k_viterbi(
    const float* __restrict__ feats, const float* __restrict__ trans,
    float* __restrict__ out)
{
    __shared__ unsigned char bp[4][T_SEQ * NTAG];
    int tid = threadIdx.x;
    int wv = tid >> 6, lane = tid & 63;
    int b = blockIdx.x * 4 + wv;
    int i = (lane < NTAG) ? lane : 0;
    bool act = lane < NTAG;
    float trow[NTAG];
#pragma unroll
    for (int j = 0; j < NTAG; ++j) trow[j] = trans[i * NTAG + j];
    float fv = (lane == TAG_START) ? 0.0f : NEGV;
    for (int t = 0; t < T_SEQ; ++t) {
        float m = -3.0e38f; int arg = 0;
#pragma unroll
        for (int j = 0; j < NTAG; ++j) {
            float fvj = __shfl(fv, j, 64);
            float sc = fvj + trow[j];
            if (sc > m) { m = sc; arg = j; }
        }
        float ft = feats[((size_t)t * NTAG + i) * 64 + b];
        fv = m + ft;
        if (act) bp[wv][t * NTAG + lane] = (unsigned char)arg;
    }
    float term = act ? (fv + trans[TAG_STOP * NTAG + i]) : -3.0e38f;
    int bi_ = lane;
#pragma unroll
    for (int off = 32; off >= 1; off >>= 1) {
        float ov = __shfl_xor(term, off, 64);
        int oi = __shfl_xor(bi_, off, 64);
        if (ov > term || (ov == term && oi < bi_)) { term = ov; bi_ = oi; }
    }
    if (lane == 0) {
        out[b] = term;
        int tag = bi_;
        float* po = out + 64 + (size_t)b * T_SEQ;
        for (int t = T_SEQ - 1; t >= 0; --t) {
            po[t] = (float)tag;
            tag = bp[wv][t * NTAG + tag];
        }
    }
}

extern "C" void kernel_launch(void* const* d_in, const int* in_sizes, int n_in,
                              void* d_out, int out_size, void* d_ws, size_t ws_size,
                              hipStream_t stream)
{
    (void)in_sizes; (void)n_in; (void)out_size;
    const int*   x     = (const int*)d_in[0];
    const float* emb   = (const float*)d_in[1];
    const float* Wout  = (const float*)d_in[2];
    const float* bout  = (const float*)d_in[3];
    const float* trans = (const float*)d_in[4];

    float* ws = (float*)d_ws;
    const size_t XS2F = (size_t)T_SEQ * 600 * NBATCH;          // f32
    const size_t XS1U = (size_t)T_SEQ * 80 * 64 * 16;          // u16
    const size_t FEA  = (size_t)T_SEQ * NTAG * NBATCH;

    float* xs2 = ws;                          // layer-1 f32 output (aliases xs0 blocks)
    u16* xs0 = (u16*)ws;                      // [T][40][64][2][8]
    u16* xs1 = (u16*)(ws + XS2F);             // [T][80][64][2][8]
    float* featB = (float*)(xs1 + XS1U);
    float* cB = featB + FEA;                  // 2*300*64
    u16* hxB = (u16*)(cB + 2 * 300 * 64);     // 4*HXE
    unsigned* flagsB = (unsigned*)(hxB + 4 * HXE);   // 64 slots * 2 dirs * FLGDIR
    unsigned* padB = flagsB + 64ULL * 2 * FLGDIR;    // layout hole kept (16 u32)
    float* preBase = (float*)(padB + 16);
    size_t fixedBytes = (size_t)((char*)preBase - (char*)ws);

    // two ping-pong slots; slot bytes = 2 bufs x Cmax (L0 view) = 4 bufs x Cmax/2 (L1 view)
    int Cmax = 512;
    while (Cmax > 16 && fixedBytes + 16ULL * Cmax * G4 * NBATCH > ws_size) Cmax >>= 1;
    if (Cmax > 64) Cmax = 64;
    int Cmax1 = Cmax >> 1;
    size_t Q0 = (size_t)Cmax  * G4 * NBATCH;   // floats per dir buf (L0)
    size_t Q1 = (size_t)Cmax1 * G4 * NBATCH;   // floats per (seg,dir) buf (L1)
    size_t slotF = 2 * Q0;                     // == 4*Q1
    float* preS[2] = { preBase, preBase + slotF };

    (void)hipMemsetAsync(hxB, 0,
        4 * HXE * sizeof(u16) + (64ULL * 2 * FLGDIR) * sizeof(unsigned), stream);
    k_gather<<<T_SEQ, 256, 0, stream>>>(x, emb, xs0);
    k_zpad<<<T_SEQ, 256, 0, stream>>>(xs1);

    for (int layer = 0; layer < 2; ++layer) {
        int base = 5 + layer * 8;
        const float* WiF = (const float*)d_in[base + 0];
        const float* WhF = (const float*)d_in[base + 1];
        const float* biF = (const float*)d_in[base + 2];
        const float* bhF = (const float*)d_in[base + 3];
        const float* WiB = (const float*)d_in[base + 4];
        const float* WhB = (const float*)d_in[base + 5];
        const float* biB = (const float*)d_in[base + 6];
        const float* bhB = (const float*)d_in[base + 7];
        const u16* xsL = (layer == 0) ? xs0 : xs1;
        int TNB = (layer == 0) ? 40 : 80;
        int NSEG = (layer == 0) ? 1 : 2;
        int CmaxL = (layer == 0) ? Cmax : Cmax1;
        size_t QL = (layer == 0) ? Q0 : Q1;

        // per-layer chunk schedule (small first chunk)
        int sizes[40], off[41], nch = 0;
        {
            int rem = T_SEQ;
            int f = (CmaxL >= 64) ? 32 : CmaxL;
            sizes[nch++] = f; rem -= f;
            while (rem > 0) { int s = rem < CmaxL ? rem : CmaxL; sizes[nch++] = s; rem -= s; }
            off[0] = 0;
            for (int i = 0; i < nch; ++i) off[i + 1] = off[i] + sizes[i];
        }

        // chunk-0 pregemm (slot 0)
        {
            int NSL0 = (sizes[0] + SSTEP - 1) / SSTEP;
            if (layer == 0)
                k_pregemm3<300><<<NSEG * 20 * NSL0, 256, 0, stream>>>(
                    xsL, TNB, WiF, WiB, preS[0], QL, 0, T_SEQ - 1, NSL0, sizes[0]);
            else
                k_pregemm3<600><<<NSEG * 20 * NSL0, 256, 0, stream>>>(
                    xsL, TNB, WiF, WiB, preS[0], QL, 0, T_SEQ - 1, NSL0, sizes[0]);
        }

        for (int ci = 0; ci < nch; ++ci) {
            int cur = ci & 1, nxt = cur ^ 1;
            int t0f = off[ci], t0b = (T_SEQ - 1) - off[ci];
            int do_pre = (ci + 1 < nch) ? 1 : 0;
            int CN = do_pre ? sizes[ci + 1] : 0;
            int NSLc = do_pre ? (CN + SSTEP - 1) / SSTEP : 1;
            int t0fN = off[ci + 1], t0bN = (T_SEQ - 1) - off[ci + 1];
            int slot = layer * 32 + ci;
            unsigned* flags = flagsB + (size_t)slot * 2 * FLGDIR;
            float* pc = preS[cur];
            float* pn = preS[nxt];
            if (layer == 0)
                k_chunk<300, 1><<<2 * NWGD + NCOMP, 256, 0, stream>>>(
                    xsL, TNB, WiF, WiB, pn, QL, t0fN, t0bN, do_pre, CN, NSLc,
                    pc, QL, WhF, WhB, biF, bhF, biB, bhB, hxB, cB,
                    xs2, xs1, t0f, t0b, sizes[ci], (ci == 0) ? 1 : 0, flags);
            else
                k_chunk<600, 0><<<2 * NWGD + NCOMP, 256, 0, stream>>>(
                    xsL, TNB, WiF, WiB, pn, QL, t0fN, t0bN, do_pre, CN, NSLc,
                    pc, QL, WhF, WhB, biF, bhF, biB, bhB, hxB, cB,
                    xs2, xs1, t0f, t0b, sizes[ci], (ci == 0) ? 1 : 0, flags);
        }
    }
    k_feats<<<T_SEQ, 256, 0, stream>>>(xs2, Wout, bout, featB);
    k_viterbi<<<16, 256, 0, stream>>>(featB, trans, (float*)d_out);
}